// Round 1
// 902.547 us; speedup vs baseline: 1.1357x; 1.1357x over previous
//
#include <hip/hip_runtime.h>

// DCT 7x7 filter-bank conv, separable. X: (32,384,384,1) f32.
// Out: zf (32,377,377,1) then hf (32,377,377,48), concatenated flat, f32.
//
// R1: coalesced hf stores. Each wave owns one output row segment (64 pixels),
// whose 64*48 floats are CONTIGUOUS in hf. Previously each thread scattered
// 12 float4 stores at 192B lane stride (64 cache lines per wave store instr,
// ~1.9 TB/s effective). Now: dump acc -> per-wave LDS buffer (padded stride
// 52 floats; bank-quad rotation 13*lane mod 8 => conflict-free-ish), then
// write back as 12 fully-coalesced 1KB wave stores.

constexpr int WIN  = 7;
constexpr int H    = 384, WD = 384;
constexpr int OH   = 377, OW = 377;
constexpr int NB   = 32;
constexpr int TX   = 64,  TY = 4;            // output tile per block (256 threads)
constexpr int LROW = TY + WIN - 1;           // 10
constexpr int LCOL = TX + WIN - 1;           // 70
constexpr int OSTR = 52;                     // LDS transpose row stride (floats), 48+4 pad

__global__ __launch_bounds__(256)
void dct_conv_kernel(const float* __restrict__ X,
                     float* __restrict__ zf,
                     float* __restrict__ hf)
{
    __shared__ float tile[LROW][LCOL];
    __shared__ __align__(16) float obuf[TY][64 * OSTR];   // 53,248 B

    const int bx  = blockIdx.x;
    const int by  = blockIdx.y;
    const int b   = blockIdx.z;
    const int tid = threadIdx.x;

    const int row0 = by * TY;
    const int col0 = bx * TX;

    const float* Xb = X + (size_t)b * H * WD;

    // ---- stage input tile into LDS (clamped; clamped values are never used
    // by valid output pixels, clamping just keeps loads in-bounds) ----
    for (int idx = tid; idx < LROW * LCOL; idx += 256) {
        const int r  = idx / LCOL;
        const int c  = idx - r * LCOL;
        const int gr = min(row0 + r, H - 1);
        const int gc = min(col0 + c, WD - 1);
        tile[r][c] = Xb[gr * WD + gc];
    }
    __syncthreads();

    const int tx = tid & 63;
    const int ty = tid >> 6;
    const int i  = row0 + ty;          // one wave == one output row segment
    const int j  = col0 + tx;

    // D[k][n] = 2*cos(pi*k*(2n+1)/14)
    constexpr float D[7][7] = {
        { 2.0f,                 2.0f,                 2.0f,                 2.0f,  2.0f,                 2.0f,                 2.0f                },
        { 1.9498558243636472f,  1.5636629649360596f,  0.8677674782351165f,  0.0f, -0.8677674782351165f, -1.5636629649360596f, -1.9498558243636472f },
        { 1.8019377358048383f,  0.4450418679126289f, -1.2469796037174672f, -2.0f, -1.2469796037174672f,  0.4450418679126289f,  1.8019377358048383f },
        { 1.5636629649360596f, -0.8677674782351165f, -1.9498558243636472f,  0.0f,  1.9498558243636472f,  0.8677674782351165f, -1.5636629649360596f },
        { 1.2469796037174672f, -1.8019377358048383f, -0.4450418679126289f,  2.0f, -0.4450418679126289f, -1.8019377358048383f,  1.2469796037174672f },
        { 0.8677674782351165f, -1.9498558243636472f,  1.5636629649360596f,  0.0f, -1.5636629649360596f,  1.9498558243636472f, -0.8677674782351165f },
        { 0.4450418679126289f, -1.2469796037174672f,  1.8019377358048383f, -2.0f,  1.8019377358048383f, -1.2469796037174672f,  0.4450418679126289f },
    };

    float acc[49];
#pragma unroll
    for (int c = 0; c < 49; ++c) acc[c] = 0.0f;

    // streamed separable DCT: for each patch row m, 1-D DCT along n, then
    // accumulate D[k][m]*u[l] into all 49 channels.
#pragma unroll
    for (int m = 0; m < 7; ++m) {
        float row[7];
#pragma unroll
        for (int n = 0; n < 7; ++n) row[n] = tile[ty + m][tx + n];

        float u[7];
#pragma unroll
        for (int l = 0; l < 7; ++l) {
            float s = D[l][0] * row[0];
#pragma unroll
            for (int n = 1; n < 7; ++n) s = fmaf(D[l][n], row[n], s);
            u[l] = s;
        }
#pragma unroll
        for (int k = 0; k < 7; ++k) {
            const float dk = D[k][m];
#pragma unroll
            for (int l = 0; l < 7; ++l) acc[k * 7 + l] = fmaf(dk, u[l], acc[k * 7 + l]);
        }
    }

    const int bi = b * OH + i;

    // ---- zf: naturally coalesced (consecutive lanes -> consecutive dwords) ----
    if (i < OH && j < OW) {
        zf[(size_t)bi * OW + j] = acc[0];
    }

    // ---- hf: transpose through per-wave LDS, then coalesced 1KB wave stores ----
    float* ob = obuf[ty];
#pragma unroll
    for (int q = 0; q < 12; ++q) {
        // dword addr = 52*tx + 4q : 16B aligned; bank-quad = (13*tx+q) mod 8
        *reinterpret_cast<float4*>(ob + tx * OSTR + 4 * q) =
            make_float4(acc[4 * q + 1], acc[4 * q + 2],
                        acc[4 * q + 3], acc[4 * q + 4]);
    }
    // wave64 is lockstep; only need LDS writes retired before cross-lane reads.
    asm volatile("s_waitcnt lgkmcnt(0)" ::: "memory");

    const int V = (i < OH) ? min(TX, OW - col0) : 0;   // valid pixels in this wave's row
    if (V > 0) {
        float* dst = hf + (size_t)(bi * OW + col0) * 48;   // contiguous 64*48 floats
        const int lim = V * 12;                            // valid float4 count
#pragma unroll
        for (int r = 0; r < 12; ++r) {
            const int f = r * 64 + tx;       // float4 index within segment
            const int p = f / 12;            // source pixel (magic-mul by compiler)
            // LDS dword addr = 4*f + 4*p  (== 52*p + (4f - 48p))
            const float4 v = *reinterpret_cast<const float4*>(ob + 4 * f + 4 * p);
            if (f < lim) {
                *reinterpret_cast<float4*>(dst + 4 * f) = v;  // 1KB contiguous per wave
            }
        }
    }
}

extern "C" void kernel_launch(void* const* d_in, const int* in_sizes, int n_in,
                              void* d_out, int out_size, void* d_ws, size_t ws_size,
                              hipStream_t stream) {
    const float* X = (const float*)d_in[0];
    float* out = (float*)d_out;
    float* zf = out;
    float* hf = out + (size_t)NB * OH * OW;   // zf is (32,377,377,1) flat

    dim3 grid((OW + TX - 1) / TX, (OH + TY - 1) / TY, NB);  // 6 x 95 x 32
    dct_conv_kernel<<<grid, dim3(256), 0, stream>>>(X, zf, hf);
}